// Round 1
// baseline (239.884 us; speedup 1.0000x reference)
//
#include <hip/hip_runtime.h>
#include <math.h>

#define NN  50000
#define NE  1600000
#define NEP 500000
#define DIN 64
#define DE  32

#define BKT_SH 7                 // 128 nodes per bucket
#define NB     391               // ceil(NN / 128)
#define S1B    250               // sort blocks
#define CHK    6400              // NE / S1B
#define HB     64                // histogram blocks (u8 counters safe: per-chunk per-node count << 255)
#define HCHK   25000             // NE / HB
#define HWRD   12500             // NN/4 packed u8x4 count-words
#define XWB    3125              // NN/16 xw1 blocks

typedef float f4 __attribute__((ext_vector_type(4)));

// ---------------- bf16 pack/unpack helpers (RNE) ----------------
__device__ __forceinline__ unsigned f2b(float f) {
    unsigned u = __float_as_uint(f);
    return (u + 0x7FFFu + ((u >> 16) & 1u)) >> 16;
}
__device__ __forceinline__ unsigned pack2(float a, float b) {
    return f2b(a) | (f2b(b) << 16);
}
__device__ __forceinline__ float blo(unsigned u) { return __uint_as_float(u << 16); }
__device__ __forceinline__ float bhi(unsigned u) { return __uint_as_float(u & 0xFFFF0000u); }

// ---------------- H1|S1 merged: blocks [0,HB) = src histogram (u8x4); [HB,..) = dst bucket counts ----
__global__ __launch_bounds__(256) void k_h1s1(const int* __restrict__ src,
                                              const int* __restrict__ dst,
                                              unsigned* __restrict__ partial,
                                              int* __restrict__ T) {
    __shared__ unsigned h[HWRD];        // 50 KB
    int t = threadIdx.x;
    if (blockIdx.x < HB) {
        for (int i = t; i < HWRD; i += 256) h[i] = 0;
        __syncthreads();
        int beg = blockIdx.x * HCHK;
        for (int i = beg + t; i < beg + HCHK; i += 256) {
            int s = src[i];
            atomicAdd(&h[s >> 2], 1u << ((s & 3) * 8));
        }
        __syncthreads();
        unsigned* p = partial + (size_t)blockIdx.x * HWRD;
        for (int i = t; i < HWRD; i += 256)
            __builtin_nontemporal_store(h[i], p + i);       // coalesced, non-atomic, stream
    } else {
        int b = blockIdx.x - HB;
        int* cd = (int*)h;
        for (int i = t; i < NB; i += 256) cd[i] = 0;
        __syncthreads();
        int beg = b * CHK;
        for (int i = beg + t; i < beg + CHK; i += 256)
            atomicAdd(&cd[dst[i] >> BKT_SH], 1);
        __syncthreads();
        for (int i = t; i < NB; i += 256) T[b * NB + i] = cd[i];
    }
}

// ---------------- S2H: block0 = column scan T -> Base + BS; blocks 1.. = u8 hist reduce -> degs ----
__global__ __launch_bounds__(512) void k_s2h(const int* __restrict__ T,
                                             int* __restrict__ Base,
                                             int* __restrict__ BS,
                                             const unsigned* __restrict__ partial,
                                             int* __restrict__ degs) {
    int t = threadIdx.x;
    if (blockIdx.x == 0) {
        __shared__ int tot[512];
        int run = 0;
        if (t < NB) {
            for (int b = 0; b < S1B; b++) {
                Base[b * NB + t] = run;
                run += T[b * NB + t];
            }
        }
        tot[t] = (t < NB) ? run : 0;
        __syncthreads();
        for (int off = 1; off < 512; off <<= 1) {
            int v = (t >= off) ? tot[t - off] : 0;
            __syncthreads();
            tot[t] += v;
            __syncthreads();
        }
        if (t < NB) BS[t] = (t == 0) ? 0 : tot[t - 1];
        if (t == 0) BS[NB] = NE;
    } else {
        int w = (blockIdx.x - 1) * 512 + t;
        if (w < HWRD) {
            int c0 = 0, c1 = 0, c2 = 0, c3 = 0;
            for (int b = 0; b < HB; b++) {
                unsigned v = __builtin_nontemporal_load(partial + (size_t)b * HWRD + w);
                c0 += (int)(v & 0xFFu);
                c1 += (int)((v >> 8) & 0xFFu);
                c2 += (int)((v >> 16) & 0xFFu);
                c3 += (int)(v >> 24);
            }
            ((int4*)degs)[w] = make_int4(c0, c1, c2, c3);
        }
    }
}

// ---------------- S3: dst-keyed block-local sort; counts preloaded from T ----------------
__global__ __launch_bounds__(512) void k_s3(const int* __restrict__ src,
                                            const int* __restrict__ dst,
                                            const int* __restrict__ T,
                                            const int* __restrict__ Base,
                                            const int* __restrict__ BS,
                                            unsigned* __restrict__ tmp) {
    __shared__ int scn[512];
    __shared__ int delta[NB];
    __shared__ int cur[NB];
    __shared__ unsigned buf[CHK];       // 25.6 KB
    int t = threadIdx.x;
    int beg = blockIdx.x * CHK;
    scn[t] = (t < NB) ? T[blockIdx.x * NB + t] : 0;
    __syncthreads();
    for (int off = 1; off < 512; off <<= 1) {
        int v = (t >= off) ? scn[t - off] : 0;
        __syncthreads();
        scn[t] += v;
        __syncthreads();
    }
    if (t < NB) {
        int ls = (t == 0) ? 0 : scn[t - 1];
        cur[t] = ls;
        delta[t] = Base[blockIdx.x * NB + t] + BS[t] - ls;
    }
    __syncthreads();
    for (int i = t; i < CHK; i += 512) {
        int d = dst[beg + i];
        int s = src[beg + i];
        int lp = atomicAdd(&cur[d >> BKT_SH], 1);
        buf[lp] = (unsigned)s | ((unsigned)d << 16);
    }
    __syncthreads();
    for (int i = t; i < CHK; i += 512) {
        unsigned e = buf[i];
        tmp[delta[e >> (16 + BKT_SH)] + i] = e;
    }
}

// ---------------- S4|XW1 merged (8 KB LDS): [0,NB) = CSR build (scattered store); [NB,..) = x@W1 ----
__global__ __launch_bounds__(256) void k_s4x(const unsigned* __restrict__ tmp,
                                             const int* __restrict__ BS,
                                             int* __restrict__ csr,
                                             int* __restrict__ rowptr,
                                             const float* __restrict__ x,
                                             const float* __restrict__ W1,
                                             const int* __restrict__ degs,
                                             unsigned* __restrict__ xw1b) {
    __shared__ float sW[DIN * DE];      // 8 KB union (s4 branch uses first 384 ints)
    int t = threadIdx.x;
    if (blockIdx.x < NB) {
        int* cnt = (int*)sW;
        int* scn = cnt + 128;
        int* cur = cnt + 256;
        int p = blockIdx.x;
        int ebeg = BS[p], eend = BS[p + 1];
        int ne = eend - ebeg;
        if (t < 128) cnt[t] = 0;
        __syncthreads();
        for (int i = t; i < ne; i += 256)
            atomicAdd(&cnt[(tmp[ebeg + i] >> 16) & 127], 1);
        __syncthreads();
        if (t < 128) scn[t] = cnt[t];
        __syncthreads();
        for (int off = 1; off < 128; off <<= 1) {
            int v = 0;
            if (t < 128 && t >= off) v = scn[t - off];
            __syncthreads();
            if (t < 128) scn[t] += v;
            __syncthreads();
        }
        if (t < 128) {
            int ex = (t == 0) ? 0 : scn[t - 1];
            cur[t] = ex;
            int node = (p << BKT_SH) + t;
            if (node < NN) rowptr[node] = ebeg + ex;
        }
        if (p == NB - 1 && t == 0) rowptr[NN] = NE;
        __syncthreads();
        for (int i = t; i < ne; i += 256) {
            unsigned e = tmp[ebeg + i];
            int lp = atomicAdd(&cur[(e >> 16) & 127], 1);
            csr[ebeg + lp] = (int)(e & 0xFFFFu);   // scattered within 16 KB bucket range (L2-absorbed)
        }
    } else {
        for (int i = t; i < DIN * DE; i += 256) sW[i] = W1[i];
        __syncthreads();
        int r  = (blockIdx.x - NB) * 16 + (t >> 4);
        int tc = t & 15;
        const float* xr = x + (size_t)r * DIN;
        float a0 = 0.f, a1 = 0.f;
#pragma unroll
        for (int k = 0; k < DIN; k++) {
            float v = xr[k];
            a0 += v * sW[k * DE + 2 * tc];
            a1 += v * sW[k * DE + 2 * tc + 1];
        }
        float ns = rsqrtf(fmaxf((float)degs[r], 1.0f));
        xw1b[r * 16 + tc] = pack2(a0 * ns, a1 * ns);
    }
}

// ---------------- accumulate helper ----------------
__device__ __forceinline__ void acc8(float* a, uint4 w) {
    a[0] += blo(w.x); a[1] += bhi(w.x);
    a[2] += blo(w.y); a[3] += bhi(w.y);
    a[4] += blo(w.z); a[5] += bhi(w.z);
    a[6] += blo(w.w); a[7] += bhi(w.w);
}

// ---------------- gather core: direct csr loads (broadcast), 8-way ILP ----------------
__device__ __forceinline__ void gather_row(const int* __restrict__ csr,
                                           const uint4* __restrict__ msg,
                                           int beg, int end, int l, float* a) {
    int idx = beg;
    for (; idx + 8 <= end; idx += 8) {
        int s0 = csr[idx],     s1 = csr[idx + 1], s2 = csr[idx + 2], s3 = csr[idx + 3];
        int s4 = csr[idx + 4], s5 = csr[idx + 5], s6 = csr[idx + 6], s7 = csr[idx + 7];
        uint4 w0 = msg[s0 * 4 + l];
        uint4 w1 = msg[s1 * 4 + l];
        uint4 w2 = msg[s2 * 4 + l];
        uint4 w3 = msg[s3 * 4 + l];
        uint4 w4 = msg[s4 * 4 + l];
        uint4 w5 = msg[s5 * 4 + l];
        uint4 w6 = msg[s6 * 4 + l];
        uint4 w7 = msg[s7 * 4 + l];
        acc8(a, w0); acc8(a, w1); acc8(a, w2); acc8(a, w3);
        acc8(a, w4); acc8(a, w5); acc8(a, w6); acc8(a, w7);
    }
    for (; idx + 4 <= end; idx += 4) {
        int s0 = csr[idx], s1 = csr[idx + 1], s2 = csr[idx + 2], s3 = csr[idx + 3];
        uint4 w0 = msg[s0 * 4 + l];
        uint4 w1 = msg[s1 * 4 + l];
        uint4 w2 = msg[s2 * 4 + l];
        uint4 w3 = msg[s3 * 4 + l];
        acc8(a, w0); acc8(a, w1); acc8(a, w2); acc8(a, w3);
    }
    for (; idx < end; idx++) {
        uint4 w = msg[csr[idx] * 4 + l];
        acc8(a, w);
    }
}

// ---------------- gather layer 1: 8 lanes/row (2-way edge split), relu/bias/scale -> bf16 out ----
__global__ __launch_bounds__(256) void k_g1(const int* __restrict__ rowptr,
                                            const int* __restrict__ csr,
                                            const uint4* __restrict__ msg,
                                            const int* __restrict__ degs,
                                            const float* __restrict__ b1,
                                            uint4* __restrict__ out) {
    int t = blockIdx.x * 256 + threadIdx.x;
    int r = t >> 3;
    int l = t & 3;
    int h = (t >> 2) & 1;
    if (r >= NN) return;
    int beg = rowptr[r];
    int end = rowptr[r + 1];
    int mid = beg + ((end - beg) >> 1);
    float a[8] = {0, 0, 0, 0, 0, 0, 0, 0};
    gather_row(csr, msg, h ? mid : beg, h ? end : mid, l, a);
#pragma unroll
    for (int k = 0; k < 8; k++) a[k] += __shfl_xor(a[k], 4);   // combine the two halves
    if (h) return;
    float scd = rsqrtf(fmaxf((float)(end - beg), 1.0f));
    float scs = rsqrtf(fmaxf((float)degs[r], 1.0f));
    const float4* b14 = (const float4*)b1;
    float4 bb0 = b14[2 * l], bb1 = b14[2 * l + 1];
    float o0 = fmaxf(scd * a[0] + bb0.x, 0.f) * scs;
    float o1 = fmaxf(scd * a[1] + bb0.y, 0.f) * scs;
    float o2 = fmaxf(scd * a[2] + bb0.z, 0.f) * scs;
    float o3 = fmaxf(scd * a[3] + bb0.w, 0.f) * scs;
    float o4 = fmaxf(scd * a[4] + bb1.x, 0.f) * scs;
    float o5 = fmaxf(scd * a[5] + bb1.y, 0.f) * scs;
    float o6 = fmaxf(scd * a[6] + bb1.z, 0.f) * scs;
    float o7 = fmaxf(scd * a[7] + bb1.w, 0.f) * scs;
    out[r * 4 + l] = make_uint4(pack2(o0, o1), pack2(o2, o3), pack2(o4, o5), pack2(o6, o7));
}

// ---------------- gather layer 2 + epilogue, 8 lanes/row ----------------
// Lane (t&3) owns k-block [8*(t&3), +8) of the aggregate; lane (t&7) owns h2 columns [8*(t&7), +8).
// j<4 lanes produce mu columns, j>=4 produce log_var -> sigma & z; mu crosses via one shfl_xor(4).
__global__ __launch_bounds__(256) void k_g2f(const int* __restrict__ rowptr,
                                             const int* __restrict__ csr,
                                             const uint4* __restrict__ msg,
                                             const float* __restrict__ W2,
                                             const float* __restrict__ b2,
                                             const float* __restrict__ eps,
                                             float* __restrict__ mu,
                                             float* __restrict__ sigma,
                                             unsigned* __restrict__ zb) {
    __shared__ float sW[DE * 64];       // 8 KB
    __shared__ float sb[64];
    int t = threadIdx.x;
    for (int i = t; i < DE * 64; i += 256) sW[i] = W2[i];
    if (t < 64) sb[t] = b2[t];
    __syncthreads();                    // only barrier: before any imbalanced work
    int g = blockIdx.x * 256 + t;
    int r = g >> 3;
    int l = g & 3;
    int j = g & 7;
    int h = (g >> 2) & 1;
    if (r >= NN) return;
    int beg = rowptr[r];
    int end = rowptr[r + 1];
    int mid = beg + ((end - beg) >> 1);
    float a[8] = {0, 0, 0, 0, 0, 0, 0, 0};
    gather_row(csr, msg, h ? mid : beg, h ? end : mid, l, a);
#pragma unroll
    for (int k = 0; k < 8; k++) a[k] += __shfl_xor(a[k], 4);   // combine halves
    float scd = rsqrtf(fmaxf((float)(end - beg), 1.0f));
#pragma unroll
    for (int k = 0; k < 8; k++) a[k] *= scd;
    // lane j owns h2 columns [8j, 8j+8)
    int cbase = 8 * j;
    float o3[8];
#pragma unroll
    for (int c = 0; c < 8; c++) o3[c] = sb[cbase + c];
#pragma unroll
    for (int d = 0; d < 4; d++) {
        int kb = 8 * (l ^ d);           // k-block held by partner lane (within 4-group)
#pragma unroll
        for (int k = 0; k < 8; k++) {
            float av = (d == 0) ? a[k] : __shfl_xor(a[k], d);
            const float* wrow = sW + (kb + k) * 64 + cbase;
#pragma unroll
            for (int c = 0; c < 8; c++) o3[c] += av * wrow[c];
        }
    }
    // j<4: mu cols [8j, 8j+8). j>=4: log_var cols [8(j-4), 8(j-4)+8).
    if (j < 4) {
        f4* mp = (f4*)(mu + (size_t)r * DE + cbase);
        f4 m0 = {o3[0], o3[1], o3[2], o3[3]};
        f4 m1 = {o3[4], o3[5], o3[6], o3[7]};
        __builtin_nontemporal_store(m0, mp);
        __builtin_nontemporal_store(m1, mp + 1);
    }
    float muv[8];
#pragma unroll
    for (int c = 0; c < 8; c++) muv[c] = __shfl_xor(o3[c], 4); // mu from partner lane j-4
    if (j >= 4) {
        int cc = cbase - DE;            // 8*(j-4)
        const f4* ep = (const f4*)(eps + (size_t)r * DE + cc);
        f4 e0 = __builtin_nontemporal_load(ep);
        f4 e1 = __builtin_nontemporal_load(ep + 1);
        float ev[8] = {e0.x, e0.y, e0.z, e0.w, e1.x, e1.y, e1.z, e1.w};
        float sgv[8], zv[8];
#pragma unroll
        for (int c = 0; c < 8; c++) {
            sgv[c] = expf(0.5f * o3[c]);
            zv[c]  = muv[c] + sgv[c] * ev[c];
        }
        f4* sp = (f4*)(sigma + (size_t)r * DE + cc);
        f4 s0 = {sgv[0], sgv[1], sgv[2], sgv[3]};
        f4 s1 = {sgv[4], sgv[5], sgv[6], sgv[7]};
        __builtin_nontemporal_store(s0, sp);
        __builtin_nontemporal_store(s1, sp + 1);
        uint4* zp = (uint4*)(zb + (size_t)r * 16 + (j - 4) * 4);
        zp[0] = make_uint4(pack2(zv[0], zv[1]), pack2(zv[2], zv[3]),
                           pack2(zv[4], zv[5]), pack2(zv[6], zv[7]));
    }
}

// ---------------- merged edge dot: 4 lanes/edge, uint4 loads, NT index/out streams ----------------
__global__ __launch_bounds__(256) void k_dot2(const uint4* __restrict__ zb4,
                                              const int* __restrict__ pu,
                                              const int* __restrict__ pv,
                                              const int* __restrict__ nu,
                                              const int* __restrict__ nv,
                                              float* __restrict__ out) {
    int t = blockIdx.x * 256 + threadIdx.x;
    int e = t >> 2;
    int l = t & 3;
    if (e < 2 * NEP) {
        int ee = (e < NEP) ? e : e - NEP;
        const int* uu = (e < NEP) ? pu : nu;
        const int* vv = (e < NEP) ? pv : nv;
        int a = __builtin_nontemporal_load(uu + ee);
        int b = __builtin_nontemporal_load(vv + ee);
        uint4 za = zb4[a * 4 + l];
        uint4 zc = zb4[b * 4 + l];
        float s = blo(za.x) * blo(zc.x) + bhi(za.x) * bhi(zc.x)
                + blo(za.y) * blo(zc.y) + bhi(za.y) * bhi(zc.y)
                + blo(za.z) * blo(zc.z) + bhi(za.z) * bhi(zc.z)
                + blo(za.w) * blo(zc.w) + bhi(za.w) * bhi(zc.w);
        s += __shfl_xor(s, 1);
        s += __shfl_xor(s, 2);
        if (l == 0) __builtin_nontemporal_store(s, out + e);
    }
}

extern "C" void kernel_launch(void* const* d_in, const int* in_sizes, int n_in,
                              void* d_out, int out_size, void* d_ws, size_t ws_size,
                              hipStream_t stream) {
    const float* x    = (const float*)d_in[0];
    const float* W1   = (const float*)d_in[1];
    const float* b1   = (const float*)d_in[2];
    const float* W2   = (const float*)d_in[3];
    const float* b2   = (const float*)d_in[4];
    const float* eps  = (const float*)d_in[5];
    const int*   esrc = (const int*)d_in[6];
    const int*   edst = (const int*)d_in[7];
    const int*   psrc = (const int*)d_in[8];
    const int*   pdst = (const int*)d_in[9];
    const int*   gsrc = (const int*)d_in[10];
    const int*   gdst = (const int*)d_in[11];

    float* out = (float*)d_out;
    float* pos = out;                      // pos[NEP], neg[NEP] contiguous
    float* mu  = out + 2 * NEP;
    float* sg  = out + 2 * NEP + NN * DE;

    // ---- workspace layout (word offsets) ----
    int* wi = (int*)d_ws;
    int*      rowptr  = wi;                                   // 50001
    int*      T       = wi + 50001;                           // 97750 (counts, preserved)
    int*      Base    = wi + 147751;                          // 97750
    int*      BS      = wi + 245501;                          // 392
    int*      degs    = wi + 245896;                          // 50000 (16B-aligned for int4)
    int*      csr     = wi + 295896;                          // NE
    unsigned* partial = (unsigned*)(wi + 1895896);            // HB*HWRD = 800,000
    unsigned* tmp     = (unsigned*)(wi + 3495896);            // NE (own region: s4 runs with xw1)
    unsigned* P0      = (unsigned*)(wi + 5095896);            // 800000: xw1b, later zb (16B-aligned)
    unsigned* P1      = P0 + 16 * NN;                         // 800000: h1b

    k_h1s1<<<HB + S1B, 256, 0, stream>>>(esrc, edst, partial, T);
    k_s2h <<<1 + (HWRD + 511) / 512, 512, 0, stream>>>(T, Base, BS, partial, degs);
    k_s3  <<<S1B, 512, 0, stream>>>(esrc, edst, T, Base, BS, tmp);
    k_s4x <<<NB + XWB, 256, 0, stream>>>(tmp, BS, csr, rowptr, x, W1, degs, P0);
    k_g1  <<<(NN * 8 + 255) / 256, 256, 0, stream>>>(rowptr, csr, (const uint4*)P0, degs, b1, (uint4*)P1);
    k_g2f <<<(NN * 8 + 255) / 256, 256, 0, stream>>>(rowptr, csr, (const uint4*)P1, W2, b2, eps, mu, sg, P0);
    k_dot2<<<(2 * NEP * 4) / 256, 256, 0, stream>>>((const uint4*)P0, psrc, pdst, gsrc, gdst, pos);
}

// Round 2
// 204.597 us; speedup vs baseline: 1.1725x; 1.1725x over previous
//
#include <hip/hip_runtime.h>
#include <math.h>

#define NN  50000
#define NE  1600000
#define NEP 500000
#define DIN 64
#define DE  32

#define BKT_SH 7                 // 128 nodes per bucket
#define NB     391               // ceil(NN / 128)
#define S1B    250               // sort blocks
#define CHK    6400              // NE / S1B
#define HB     128               // histogram blocks (u8 counters safe: per-chunk per-node count << 255)
#define HCHK   12500             // NE / HB
#define HWRD   12500             // NN/4 packed u8x4 count-words
#define XWB    3125              // NN/16 xw1 blocks

typedef float f4 __attribute__((ext_vector_type(4)));

// ---------------- bf16 pack/unpack helpers (RNE) ----------------
__device__ __forceinline__ unsigned f2b(float f) {
    unsigned u = __float_as_uint(f);
    return (u + 0x7FFFu + ((u >> 16) & 1u)) >> 16;
}
__device__ __forceinline__ unsigned pack2(float a, float b) {
    return f2b(a) | (f2b(b) << 16);
}
__device__ __forceinline__ float blo(unsigned u) { return __uint_as_float(u << 16); }
__device__ __forceinline__ float bhi(unsigned u) { return __uint_as_float(u & 0xFFFF0000u); }

// ---------------- H1|S1 merged: blocks [0,HB) = src histogram (u8x4); [HB,..) = dst bucket counts ----
// Both inner loops manually 8-wide batched: issue 8 independent global loads, then 8 LDS atomics,
// so one memory latency covers 8 edges instead of 1 (round-1 showed ~1150 cy/edge = unpipelined).
__global__ __launch_bounds__(256) void k_h1s1(const int* __restrict__ src,
                                              const int* __restrict__ dst,
                                              unsigned* __restrict__ partial,
                                              int* __restrict__ T) {
    __shared__ unsigned h[HWRD];        // 50 KB
    int t = threadIdx.x;
    if (blockIdx.x < HB) {
        for (int i = t; i < HWRD; i += 256) h[i] = 0;
        __syncthreads();
        int beg = blockIdx.x * HCHK;
        const int ev = beg + HCHK;
        int i = beg + t;
        for (; i + 1792 < ev; i += 2048) {
            int s0 = src[i],        s1 = src[i + 256],  s2 = src[i + 512],  s3 = src[i + 768];
            int s4 = src[i + 1024], s5 = src[i + 1280], s6 = src[i + 1536], s7 = src[i + 1792];
            atomicAdd(&h[s0 >> 2], 1u << ((s0 & 3) * 8));
            atomicAdd(&h[s1 >> 2], 1u << ((s1 & 3) * 8));
            atomicAdd(&h[s2 >> 2], 1u << ((s2 & 3) * 8));
            atomicAdd(&h[s3 >> 2], 1u << ((s3 & 3) * 8));
            atomicAdd(&h[s4 >> 2], 1u << ((s4 & 3) * 8));
            atomicAdd(&h[s5 >> 2], 1u << ((s5 & 3) * 8));
            atomicAdd(&h[s6 >> 2], 1u << ((s6 & 3) * 8));
            atomicAdd(&h[s7 >> 2], 1u << ((s7 & 3) * 8));
        }
        for (; i < ev; i += 256) {
            int s = src[i];
            atomicAdd(&h[s >> 2], 1u << ((s & 3) * 8));
        }
        __syncthreads();
        unsigned* p = partial + (size_t)blockIdx.x * HWRD;
        for (int i2 = t; i2 < HWRD; i2 += 256) p[i2] = h[i2];   // coalesced, stays in L2/L3 for s2h
    } else {
        int b = blockIdx.x - HB;
        int* cd = (int*)h;
        for (int i = t; i < NB; i += 256) cd[i] = 0;
        __syncthreads();
        int beg = b * CHK;
        const int ev = beg + CHK;
        int i = beg + t;
        for (; i + 1792 < ev; i += 2048) {
            int d0 = dst[i],        d1 = dst[i + 256],  d2 = dst[i + 512],  d3 = dst[i + 768];
            int d4 = dst[i + 1024], d5 = dst[i + 1280], d6 = dst[i + 1536], d7 = dst[i + 1792];
            atomicAdd(&cd[d0 >> BKT_SH], 1);
            atomicAdd(&cd[d1 >> BKT_SH], 1);
            atomicAdd(&cd[d2 >> BKT_SH], 1);
            atomicAdd(&cd[d3 >> BKT_SH], 1);
            atomicAdd(&cd[d4 >> BKT_SH], 1);
            atomicAdd(&cd[d5 >> BKT_SH], 1);
            atomicAdd(&cd[d6 >> BKT_SH], 1);
            atomicAdd(&cd[d7 >> BKT_SH], 1);
        }
        for (; i < ev; i += 256)
            atomicAdd(&cd[dst[i] >> BKT_SH], 1);
        __syncthreads();
        for (int i2 = t; i2 < NB; i2 += 256) T[b * NB + i2] = cd[i2];
    }
}

// ---------------- S2H: block0 = column scan T -> Base + BS; blocks 1.. = u8 hist reduce -> degs ----
__global__ __launch_bounds__(512) void k_s2h(const int* __restrict__ T,
                                             int* __restrict__ Base,
                                             int* __restrict__ BS,
                                             const unsigned* __restrict__ partial,
                                             int* __restrict__ degs) {
    int t = threadIdx.x;
    if (blockIdx.x == 0) {
        __shared__ int tot[512];
        int run = 0;
        if (t < NB) {
            for (int b = 0; b < S1B; b++) {
                Base[b * NB + t] = run;
                run += T[b * NB + t];
            }
        }
        tot[t] = (t < NB) ? run : 0;
        __syncthreads();
        for (int off = 1; off < 512; off <<= 1) {
            int v = (t >= off) ? tot[t - off] : 0;
            __syncthreads();
            tot[t] += v;
            __syncthreads();
        }
        if (t < NB) BS[t] = (t == 0) ? 0 : tot[t - 1];
        if (t == 0) BS[NB] = NE;
    } else {
        int w = (blockIdx.x - 1) * 512 + t;
        if (w < HWRD) {
            int c0 = 0, c1 = 0, c2 = 0, c3 = 0;
#pragma unroll 8
            for (int b = 0; b < HB; b++) {
                unsigned v = partial[(size_t)b * HWRD + w];
                c0 += (int)(v & 0xFFu);
                c1 += (int)((v >> 8) & 0xFFu);
                c2 += (int)((v >> 16) & 0xFFu);
                c3 += (int)(v >> 24);
            }
            ((int4*)degs)[w] = make_int4(c0, c1, c2, c3);
        }
    }
}

// ---------------- S3: dst-keyed block-local sort; counts preloaded from T; binning loop batched ----
__global__ __launch_bounds__(512) void k_s3(const int* __restrict__ src,
                                            const int* __restrict__ dst,
                                            const int* __restrict__ T,
                                            const int* __restrict__ Base,
                                            const int* __restrict__ BS,
                                            unsigned* __restrict__ tmp) {
    __shared__ int scn[512];
    __shared__ int delta[NB];
    __shared__ int cur[NB];
    __shared__ unsigned buf[CHK];       // 25.6 KB
    int t = threadIdx.x;
    int beg = blockIdx.x * CHK;
    scn[t] = (t < NB) ? T[blockIdx.x * NB + t] : 0;
    __syncthreads();
    for (int off = 1; off < 512; off <<= 1) {
        int v = (t >= off) ? scn[t - off] : 0;
        __syncthreads();
        scn[t] += v;
        __syncthreads();
    }
    if (t < NB) {
        int ls = (t == 0) ? 0 : scn[t - 1];
        cur[t] = ls;
        delta[t] = Base[blockIdx.x * NB + t] + BS[t] - ls;
    }
    __syncthreads();
    {
        const int ev = beg + CHK;
        int i = beg + t;
        for (; i + 1536 < ev; i += 2048) {
            int d0 = dst[i],        s0 = src[i];
            int d1 = dst[i + 512],  s1 = src[i + 512];
            int d2 = dst[i + 1024], s2 = src[i + 1024];
            int d3 = dst[i + 1536], s3 = src[i + 1536];
            int l0 = atomicAdd(&cur[d0 >> BKT_SH], 1); buf[l0] = (unsigned)s0 | ((unsigned)d0 << 16);
            int l1 = atomicAdd(&cur[d1 >> BKT_SH], 1); buf[l1] = (unsigned)s1 | ((unsigned)d1 << 16);
            int l2 = atomicAdd(&cur[d2 >> BKT_SH], 1); buf[l2] = (unsigned)s2 | ((unsigned)d2 << 16);
            int l3 = atomicAdd(&cur[d3 >> BKT_SH], 1); buf[l3] = (unsigned)s3 | ((unsigned)d3 << 16);
        }
        for (; i < ev; i += 512) {
            int d = dst[i];
            int s = src[i];
            int lp = atomicAdd(&cur[d >> BKT_SH], 1);
            buf[lp] = (unsigned)s | ((unsigned)d << 16);
        }
    }
    __syncthreads();
    for (int i = t; i < CHK; i += 512) {
        unsigned e = buf[i];
        tmp[delta[e >> (16 + BKT_SH)] + i] = e;
    }
}

// ---------------- S4|XW1 merged (8 KB LDS): [0,NB) = CSR build (batched); [NB,..) = x@W1 ----
__global__ __launch_bounds__(256) void k_s4x(const unsigned* __restrict__ tmp,
                                             const int* __restrict__ BS,
                                             int* __restrict__ csr,
                                             int* __restrict__ rowptr,
                                             const float* __restrict__ x,
                                             const float* __restrict__ W1,
                                             const int* __restrict__ degs,
                                             unsigned* __restrict__ xw1b) {
    __shared__ float sW[DIN * DE];      // 8 KB union (s4 branch uses first 384 ints)
    int t = threadIdx.x;
    if (blockIdx.x < NB) {
        int* cnt = (int*)sW;
        int* scn = cnt + 128;
        int* cur = cnt + 256;
        int p = blockIdx.x;
        int ebeg = BS[p], eend = BS[p + 1];
        int ne = eend - ebeg;
        if (t < 128) cnt[t] = 0;
        __syncthreads();
        {
            int i = t;
            for (; i + 768 < ne; i += 1024) {
                unsigned e0 = tmp[ebeg + i];
                unsigned e1 = tmp[ebeg + i + 256];
                unsigned e2 = tmp[ebeg + i + 512];
                unsigned e3 = tmp[ebeg + i + 768];
                atomicAdd(&cnt[(e0 >> 16) & 127], 1);
                atomicAdd(&cnt[(e1 >> 16) & 127], 1);
                atomicAdd(&cnt[(e2 >> 16) & 127], 1);
                atomicAdd(&cnt[(e3 >> 16) & 127], 1);
            }
            for (; i < ne; i += 256)
                atomicAdd(&cnt[(tmp[ebeg + i] >> 16) & 127], 1);
        }
        __syncthreads();
        if (t < 128) scn[t] = cnt[t];
        __syncthreads();
        for (int off = 1; off < 128; off <<= 1) {
            int v = 0;
            if (t < 128 && t >= off) v = scn[t - off];
            __syncthreads();
            if (t < 128) scn[t] += v;
            __syncthreads();
        }
        if (t < 128) {
            int ex = (t == 0) ? 0 : scn[t - 1];
            cur[t] = ex;
            int node = (p << BKT_SH) + t;
            if (node < NN) rowptr[node] = ebeg + ex;
        }
        if (p == NB - 1 && t == 0) rowptr[NN] = NE;
        __syncthreads();
        {
            int i = t;
            for (; i + 768 < ne; i += 1024) {
                unsigned e0 = tmp[ebeg + i];
                unsigned e1 = tmp[ebeg + i + 256];
                unsigned e2 = tmp[ebeg + i + 512];
                unsigned e3 = tmp[ebeg + i + 768];
                int l0 = atomicAdd(&cur[(e0 >> 16) & 127], 1); csr[ebeg + l0] = (int)(e0 & 0xFFFFu);
                int l1 = atomicAdd(&cur[(e1 >> 16) & 127], 1); csr[ebeg + l1] = (int)(e1 & 0xFFFFu);
                int l2 = atomicAdd(&cur[(e2 >> 16) & 127], 1); csr[ebeg + l2] = (int)(e2 & 0xFFFFu);
                int l3 = atomicAdd(&cur[(e3 >> 16) & 127], 1); csr[ebeg + l3] = (int)(e3 & 0xFFFFu);
            }
            for (; i < ne; i += 256) {
                unsigned e = tmp[ebeg + i];
                int lp = atomicAdd(&cur[(e >> 16) & 127], 1);
                csr[ebeg + lp] = (int)(e & 0xFFFFu);   // scattered within 16 KB bucket range (L2-absorbed)
            }
        }
    } else {
        for (int i = t; i < DIN * DE; i += 256) sW[i] = W1[i];
        __syncthreads();
        int r  = (blockIdx.x - NB) * 16 + (t >> 4);
        int tc = t & 15;
        const float* xr = x + (size_t)r * DIN;
        float a0 = 0.f, a1 = 0.f;
#pragma unroll
        for (int k = 0; k < DIN; k++) {
            float v = xr[k];
            a0 += v * sW[k * DE + 2 * tc];
            a1 += v * sW[k * DE + 2 * tc + 1];
        }
        float ns = rsqrtf(fmaxf((float)degs[r], 1.0f));
        xw1b[r * 16 + tc] = pack2(a0 * ns, a1 * ns);
    }
}

// ---------------- accumulate helper ----------------
__device__ __forceinline__ void acc8(float* a, uint4 w) {
    a[0] += blo(w.x); a[1] += bhi(w.x);
    a[2] += blo(w.y); a[3] += bhi(w.y);
    a[4] += blo(w.z); a[5] += bhi(w.z);
    a[6] += blo(w.w); a[7] += bhi(w.w);
}

// ---------------- gather core: direct csr loads (broadcast), 8-way ILP ----------------
__device__ __forceinline__ void gather_row(const int* __restrict__ csr,
                                           const uint4* __restrict__ msg,
                                           int beg, int end, int l, float* a) {
    int idx = beg;
    for (; idx + 8 <= end; idx += 8) {
        int s0 = csr[idx],     s1 = csr[idx + 1], s2 = csr[idx + 2], s3 = csr[idx + 3];
        int s4 = csr[idx + 4], s5 = csr[idx + 5], s6 = csr[idx + 6], s7 = csr[idx + 7];
        uint4 w0 = msg[s0 * 4 + l];
        uint4 w1 = msg[s1 * 4 + l];
        uint4 w2 = msg[s2 * 4 + l];
        uint4 w3 = msg[s3 * 4 + l];
        uint4 w4 = msg[s4 * 4 + l];
        uint4 w5 = msg[s5 * 4 + l];
        uint4 w6 = msg[s6 * 4 + l];
        uint4 w7 = msg[s7 * 4 + l];
        acc8(a, w0); acc8(a, w1); acc8(a, w2); acc8(a, w3);
        acc8(a, w4); acc8(a, w5); acc8(a, w6); acc8(a, w7);
    }
    for (; idx + 4 <= end; idx += 4) {
        int s0 = csr[idx], s1 = csr[idx + 1], s2 = csr[idx + 2], s3 = csr[idx + 3];
        uint4 w0 = msg[s0 * 4 + l];
        uint4 w1 = msg[s1 * 4 + l];
        uint4 w2 = msg[s2 * 4 + l];
        uint4 w3 = msg[s3 * 4 + l];
        acc8(a, w0); acc8(a, w1); acc8(a, w2); acc8(a, w3);
    }
    for (; idx < end; idx++) {
        uint4 w = msg[csr[idx] * 4 + l];
        acc8(a, w);
    }
}

// ---------------- gather layer 1: 8 lanes/row (2-way edge split), relu/bias/scale -> bf16 out ----
__global__ __launch_bounds__(256) void k_g1(const int* __restrict__ rowptr,
                                            const int* __restrict__ csr,
                                            const uint4* __restrict__ msg,
                                            const int* __restrict__ degs,
                                            const float* __restrict__ b1,
                                            uint4* __restrict__ out) {
    int t = blockIdx.x * 256 + threadIdx.x;
    int r = t >> 3;
    int l = t & 3;
    int h = (t >> 2) & 1;
    if (r >= NN) return;
    int beg = rowptr[r];
    int end = rowptr[r + 1];
    int mid = beg + ((end - beg) >> 1);
    float a[8] = {0, 0, 0, 0, 0, 0, 0, 0};
    gather_row(csr, msg, h ? mid : beg, h ? end : mid, l, a);
#pragma unroll
    for (int k = 0; k < 8; k++) a[k] += __shfl_xor(a[k], 4);   // combine the two halves
    if (h) return;
    float scd = rsqrtf(fmaxf((float)(end - beg), 1.0f));
    float scs = rsqrtf(fmaxf((float)degs[r], 1.0f));
    const float4* b14 = (const float4*)b1;
    float4 bb0 = b14[2 * l], bb1 = b14[2 * l + 1];
    float o0 = fmaxf(scd * a[0] + bb0.x, 0.f) * scs;
    float o1 = fmaxf(scd * a[1] + bb0.y, 0.f) * scs;
    float o2 = fmaxf(scd * a[2] + bb0.z, 0.f) * scs;
    float o3 = fmaxf(scd * a[3] + bb0.w, 0.f) * scs;
    float o4 = fmaxf(scd * a[4] + bb1.x, 0.f) * scs;
    float o5 = fmaxf(scd * a[5] + bb1.y, 0.f) * scs;
    float o6 = fmaxf(scd * a[6] + bb1.z, 0.f) * scs;
    float o7 = fmaxf(scd * a[7] + bb1.w, 0.f) * scs;
    out[r * 4 + l] = make_uint4(pack2(o0, o1), pack2(o2, o3), pack2(o4, o5), pack2(o6, o7));
}

// ---------------- gather layer 2 + epilogue, 8 lanes/row ----------------
// Lane (t&3) owns k-block [8*(t&3), +8) of the aggregate; lane (t&7) owns h2 columns [8*(t&7), +8).
// j<4 lanes produce mu columns, j>=4 produce log_var -> sigma & z; mu crosses via one shfl_xor(4).
__global__ __launch_bounds__(256) void k_g2f(const int* __restrict__ rowptr,
                                             const int* __restrict__ csr,
                                             const uint4* __restrict__ msg,
                                             const float* __restrict__ W2,
                                             const float* __restrict__ b2,
                                             const float* __restrict__ eps,
                                             float* __restrict__ mu,
                                             float* __restrict__ sigma,
                                             unsigned* __restrict__ zb) {
    __shared__ float sW[DE * 64];       // 8 KB
    __shared__ float sb[64];
    int t = threadIdx.x;
    for (int i = t; i < DE * 64; i += 256) sW[i] = W2[i];
    if (t < 64) sb[t] = b2[t];
    __syncthreads();                    // only barrier: before any imbalanced work
    int g = blockIdx.x * 256 + t;
    int r = g >> 3;
    int l = g & 3;
    int j = g & 7;
    int h = (g >> 2) & 1;
    if (r >= NN) return;
    int beg = rowptr[r];
    int end = rowptr[r + 1];
    int mid = beg + ((end - beg) >> 1);
    float a[8] = {0, 0, 0, 0, 0, 0, 0, 0};
    gather_row(csr, msg, h ? mid : beg, h ? end : mid, l, a);
#pragma unroll
    for (int k = 0; k < 8; k++) a[k] += __shfl_xor(a[k], 4);   // combine halves
    float scd = rsqrtf(fmaxf((float)(end - beg), 1.0f));
#pragma unroll
    for (int k = 0; k < 8; k++) a[k] *= scd;
    // lane j owns h2 columns [8j, 8j+8)
    int cbase = 8 * j;
    float o3[8];
#pragma unroll
    for (int c = 0; c < 8; c++) o3[c] = sb[cbase + c];
#pragma unroll
    for (int d = 0; d < 4; d++) {
        int kb = 8 * (l ^ d);           // k-block held by partner lane (within 4-group)
#pragma unroll
        for (int k = 0; k < 8; k++) {
            float av = (d == 0) ? a[k] : __shfl_xor(a[k], d);
            const float* wrow = sW + (kb + k) * 64 + cbase;
#pragma unroll
            for (int c = 0; c < 8; c++) o3[c] += av * wrow[c];
        }
    }
    // j<4: mu cols [8j, 8j+8). j>=4: log_var cols [8(j-4), 8(j-4)+8).
    if (j < 4) {
        f4* mp = (f4*)(mu + (size_t)r * DE + cbase);
        f4 m0 = {o3[0], o3[1], o3[2], o3[3]};
        f4 m1 = {o3[4], o3[5], o3[6], o3[7]};
        __builtin_nontemporal_store(m0, mp);
        __builtin_nontemporal_store(m1, mp + 1);
    }
    float muv[8];
#pragma unroll
    for (int c = 0; c < 8; c++) muv[c] = __shfl_xor(o3[c], 4); // mu from partner lane j-4
    if (j >= 4) {
        int cc = cbase - DE;            // 8*(j-4)
        const f4* ep = (const f4*)(eps + (size_t)r * DE + cc);
        f4 e0 = __builtin_nontemporal_load(ep);
        f4 e1 = __builtin_nontemporal_load(ep + 1);
        float ev[8] = {e0.x, e0.y, e0.z, e0.w, e1.x, e1.y, e1.z, e1.w};
        float sgv[8], zv[8];
#pragma unroll
        for (int c = 0; c < 8; c++) {
            sgv[c] = expf(0.5f * o3[c]);
            zv[c]  = muv[c] + sgv[c] * ev[c];
        }
        f4* sp = (f4*)(sigma + (size_t)r * DE + cc);
        f4 s0 = {sgv[0], sgv[1], sgv[2], sgv[3]};
        f4 s1 = {sgv[4], sgv[5], sgv[6], sgv[7]};
        __builtin_nontemporal_store(s0, sp);
        __builtin_nontemporal_store(s1, sp + 1);
        uint4* zp = (uint4*)(zb + (size_t)r * 16 + (j - 4) * 4);
        zp[0] = make_uint4(pack2(zv[0], zv[1]), pack2(zv[2], zv[3]),
                           pack2(zv[4], zv[5]), pack2(zv[6], zv[7]));
    }
}

// ---------------- merged edge dot: 4 lanes/edge, uint4 loads, NT index/out streams ----------------
__global__ __launch_bounds__(256) void k_dot2(const uint4* __restrict__ zb4,
                                              const int* __restrict__ pu,
                                              const int* __restrict__ pv,
                                              const int* __restrict__ nu,
                                              const int* __restrict__ nv,
                                              float* __restrict__ out) {
    int t = blockIdx.x * 256 + threadIdx.x;
    int e = t >> 2;
    int l = t & 3;
    if (e < 2 * NEP) {
        int ee = (e < NEP) ? e : e - NEP;
        const int* uu = (e < NEP) ? pu : nu;
        const int* vv = (e < NEP) ? pv : nv;
        int a = __builtin_nontemporal_load(uu + ee);
        int b = __builtin_nontemporal_load(vv + ee);
        uint4 za = zb4[a * 4 + l];
        uint4 zc = zb4[b * 4 + l];
        float s = blo(za.x) * blo(zc.x) + bhi(za.x) * bhi(zc.x)
                + blo(za.y) * blo(zc.y) + bhi(za.y) * bhi(zc.y)
                + blo(za.z) * blo(zc.z) + bhi(za.z) * bhi(zc.z)
                + blo(za.w) * blo(zc.w) + bhi(za.w) * bhi(zc.w);
        s += __shfl_xor(s, 1);
        s += __shfl_xor(s, 2);
        if (l == 0) __builtin_nontemporal_store(s, out + e);
    }
}

extern "C" void kernel_launch(void* const* d_in, const int* in_sizes, int n_in,
                              void* d_out, int out_size, void* d_ws, size_t ws_size,
                              hipStream_t stream) {
    const float* x    = (const float*)d_in[0];
    const float* W1   = (const float*)d_in[1];
    const float* b1   = (const float*)d_in[2];
    const float* W2   = (const float*)d_in[3];
    const float* b2   = (const float*)d_in[4];
    const float* eps  = (const float*)d_in[5];
    const int*   esrc = (const int*)d_in[6];
    const int*   edst = (const int*)d_in[7];
    const int*   psrc = (const int*)d_in[8];
    const int*   pdst = (const int*)d_in[9];
    const int*   gsrc = (const int*)d_in[10];
    const int*   gdst = (const int*)d_in[11];

    float* out = (float*)d_out;
    float* pos = out;                      // pos[NEP], neg[NEP] contiguous
    float* mu  = out + 2 * NEP;
    float* sg  = out + 2 * NEP + NN * DE;

    // ---- workspace layout (word offsets) ----
    int* wi = (int*)d_ws;
    int*      rowptr  = wi;                                   // 50001
    int*      T       = wi + 50001;                           // 97750 (counts, preserved)
    int*      Base    = wi + 147751;                          // 97750
    int*      BS      = wi + 245501;                          // 392
    int*      degs    = wi + 245896;                          // 50000 (16B-aligned for int4)
    int*      csr     = wi + 295896;                          // NE
    unsigned* partial = (unsigned*)(wi + 1895896);            // HB*HWRD = 1,600,000
    unsigned* tmp     = (unsigned*)(wi + 3495896);            // NE (own region: s4 runs with xw1)
    unsigned* P0      = (unsigned*)(wi + 5095896);            // 800000: xw1b, later zb (16B-aligned)
    unsigned* P1      = P0 + 16 * NN;                         // 800000: h1b

    k_h1s1<<<HB + S1B, 256, 0, stream>>>(esrc, edst, partial, T);
    k_s2h <<<1 + (HWRD + 511) / 512, 512, 0, stream>>>(T, Base, BS, partial, degs);
    k_s3  <<<S1B, 512, 0, stream>>>(esrc, edst, T, Base, BS, tmp);
    k_s4x <<<NB + XWB, 256, 0, stream>>>(tmp, BS, csr, rowptr, x, W1, degs, P0);
    k_g1  <<<(NN * 8 + 255) / 256, 256, 0, stream>>>(rowptr, csr, (const uint4*)P0, degs, b1, (uint4*)P1);
    k_g2f <<<(NN * 8 + 255) / 256, 256, 0, stream>>>(rowptr, csr, (const uint4*)P1, W2, b2, eps, mu, sg, P0);
    k_dot2<<<(2 * NEP * 4) / 256, 256, 0, stream>>>((const uint4*)P0, psrc, pdst, gsrc, gdst, pos);
}